// Round 1
// baseline (159.155 us; speedup 1.0000x reference)
//
#include <hip/hip_runtime.h>
#include <hip/hip_bf16.h>

// Problem constants
#define NT      32      // time steps
#define FEAT    128     // in/out features per step
#define TRIB    8       // band width in blocks
#define BATCH   8192
#define INSIZE  (NT*FEAT)   // 4096
#define OUTCOLS (NT*FEAT)   // 4096

typedef __bf16 bf16;
typedef __bf16 bf16x4 __attribute__((ext_vector_type(4)));
typedef __bf16 bf16x8 __attribute__((ext_vector_type(8)));
typedef float  f32x4  __attribute__((ext_vector_type(4)));

__host__ __device__ __forceinline__ int nb_of(int i){ return i < TRIB ? i + 1 : TRIB; }
__host__ __device__ __forceinline__ int lo_of(int i){ int l = i - TRIB + 1; return l > 0 ? l : 0; }
// element offset of packed bf16 band for time step i: sum_{j<i} nb(j) * 128*128
__host__ __device__ __forceinline__ long off_of(int i){
  long sum = (i <= TRIB) ? (long)i*(i+1)/2 : (long)(TRIB*(TRIB+1)/2) + (long)(i - TRIB)*TRIB;
  return sum * (long)(FEAT*FEAT);
}

// ---------------- conversion kernels ----------------

__global__ void cvt_x_kernel(const float* __restrict__ x, bf16* __restrict__ xb, long n4){
  long idx = (long)blockIdx.x * blockDim.x + threadIdx.x;
  long stride = (long)gridDim.x * blockDim.x;
  const f32x4* src = (const f32x4*)x;
  bf16x4* dst = (bf16x4*)xb;
  for (long i = idx; i < n4; i += stride){
    f32x4 v = src[i];
    bf16x4 o;
    o.x = (bf16)v.x; o.y = (bf16)v.y; o.z = (bf16)v.z; o.w = (bf16)v.w;
    dst[i] = o;
  }
}

// one block per (time step i, row n): convert band row of W (<=1024 floats) to packed bf16
__global__ void cvt_w_kernel(const float* __restrict__ w, bf16* __restrict__ wp){
  int i = blockIdx.x;      // time step
  int n = blockIdx.y;      // row within output block
  int ktl = nb_of(i) * FEAT;   // band K length (<=1024)
  int lo  = lo_of(i) * FEAT;
  long src = (long)(i*FEAT + n) * INSIZE + lo;
  long dst = off_of(i) + (long)n * ktl;
  for (int e = threadIdx.x * 4; e < ktl; e += blockDim.x * 4){
    f32x4 v = *(const f32x4*)(w + src + e);
    bf16x4 o;
    o.x = (bf16)v.x; o.y = (bf16)v.y; o.z = (bf16)v.z; o.w = (bf16)v.w;
    *(bf16x4*)(wp + dst + e) = o;
  }
}

// ---------------- banded GEMM ----------------
// BM=128 (batch rows), BN=128 (one time step's features), BK=64.
// 256 threads = 4 waves in 2x2; each wave owns 64x64 = 4x4 frags of 16x16.

#define BM 128
#define BN 128
#define BK 64

__device__ __forceinline__ void gload16(const void* g, void* l){
  __builtin_amdgcn_global_load_lds(
      (__attribute__((address_space(1))) unsigned int*)(unsigned long long)g,
      (__attribute__((address_space(3))) unsigned int*)l,
      16, 0, 0);
}

__global__ __launch_bounds__(256)
void gemm_band_kernel(const bf16* __restrict__ xb, const bf16* __restrict__ wp,
                      const float* __restrict__ bias, float* __restrict__ out){
  __shared__ __align__(16) bf16 As[BM*BK];   // [m][k] row-major, 64 bf16/row
  __shared__ __align__(16) bf16 Bs[BN*BK];   // [n][k] row-major

  const int mt = blockIdx.x;        // 0..63
  const int i  = blockIdx.y;        // 0..31 (time step)
  const int m0 = mt * BM;
  const int Kt = nb_of(i) * FEAT;   // band length
  const int lo = lo_of(i) * FEAT;
  const long wpo = off_of(i);

  const int tid  = threadIdx.x;
  const int lane = tid & 63;
  const int wid  = tid >> 6;        // 0..3
  const int wr = wid >> 1;          // wave row (0..1) -> 64 rows of M
  const int wc = wid & 1;           // wave col (0..1) -> 64 cols of N

  f32x4 acc[4][4] = {};

  const int nsteps = Kt / BK;

  for (int s = 0; s < nsteps; ++s){
    __syncthreads();                 // previous iter's LDS reads done
    const int kbase = lo + s * BK;
    // stage A and B tiles: 1024 chunks of 16B each; 8 chunks/row
    #pragma unroll
    for (int t = 0; t < 4; ++t){
      const int chunk = t*256 + wid*64 + lane;
      const int r    = chunk >> 3;       // row 0..127
      const int slot = chunk & 7;        // 8-elem slot within row
      const bf16* ga = xb + (long)(m0 + r) * INSIZE + kbase + slot*8;
      gload16(ga, (void*)&As[(t*256 + wid*64) * 8]);   // wave-uniform LDS base
      const bf16* gb = wp + wpo + (long)r * Kt + s*BK + slot*8;
      gload16(gb, (void*)&Bs[(t*256 + wid*64) * 8]);
    }
    __syncthreads();                 // staging complete (drains vmcnt)

    // fragments
    bf16x8 a[4][2], b[4][2];
    const int kcol = (lane >> 4) * 8;    // 8 contiguous k per lane-group
    #pragma unroll
    for (int mi = 0; mi < 4; ++mi){
      const int row = wr*64 + mi*16 + (lane & 15);
      #pragma unroll
      for (int ks = 0; ks < 2; ++ks)
        a[mi][ks] = *(const bf16x8*)&As[row*BK + ks*32 + kcol];
    }
    #pragma unroll
    for (int ni = 0; ni < 4; ++ni){
      const int row = wc*64 + ni*16 + (lane & 15);
      #pragma unroll
      for (int ks = 0; ks < 2; ++ks)
        b[ni][ks] = *(const bf16x8*)&Bs[row*BK + ks*32 + kcol];
    }
    #pragma unroll
    for (int ks = 0; ks < 2; ++ks)
      #pragma unroll
      for (int mi = 0; mi < 4; ++mi)
        #pragma unroll
        for (int ni = 0; ni < 4; ++ni)
          acc[mi][ni] = __builtin_amdgcn_mfma_f32_16x16x32_bf16(
              a[mi][ks], b[ni][ks], acc[mi][ni], 0, 0, 0);
  }

  // epilogue: C/D layout col = lane&15, row = (lane>>4)*4 + reg
  const int cfrag = lane & 15;
  const int rgrp  = lane >> 4;
  #pragma unroll
  for (int ni = 0; ni < 4; ++ni){
    const int gcol = i*FEAT + wc*64 + ni*16 + cfrag;
    const float bval = bias[gcol];
    #pragma unroll
    for (int mi = 0; mi < 4; ++mi){
      #pragma unroll
      for (int r2 = 0; r2 < 4; ++r2){
        const int m = m0 + wr*64 + mi*16 + rgrp*4 + r2;
        out[(long)m * OUTCOLS + gcol] = acc[mi][ni][r2] + bval;
      }
    }
  }
}

// ---------------- fallback (tiny ws): naive fp32, band-limited ----------------
__global__ void naive_kernel(const float* __restrict__ x, const float* __restrict__ w,
                             const float* __restrict__ bias, float* __restrict__ out){
  long idx = (long)blockIdx.x * blockDim.x + threadIdx.x;  // over 8192*4096
  int o = (int)(idx & (OUTCOLS - 1));
  int b = (int)(idx >> 12);
  int i = o >> 7;
  int lo = lo_of(i) * FEAT, hi = (i + 1) * FEAT;
  const float* xr = x + (long)b * INSIZE;
  const float* wr = w + (long)o * INSIZE;
  float s = bias[o];
  for (int k = lo; k < hi; k += 4){
    f32x4 xv = *(const f32x4*)(xr + k);
    f32x4 wv = *(const f32x4*)(wr + k);
    s += xv.x*wv.x + xv.y*wv.y + xv.z*wv.z + xv.w*wv.w;
  }
  out[idx] = s;
}

// ---------------- launch ----------------
extern "C" void kernel_launch(void* const* d_in, const int* in_sizes, int n_in,
                              void* d_out, int out_size, void* d_ws, size_t ws_size,
                              hipStream_t stream) {
  const float* x    = (const float*)d_in[0];
  const float* w    = (const float*)d_in[1];
  const float* bias = (const float*)d_in[2];
  // d_in[3] = mask (block-banded, reproduced analytically) — unused
  float* out = (float*)d_out;

  const size_t x_bytes = (size_t)BATCH * INSIZE * sizeof(bf16);        // 64 MiB
  const size_t w_bytes = (size_t)228 * FEAT * FEAT * sizeof(bf16);     // ~7.5 MiB packed band
  if (ws_size >= x_bytes + w_bytes){
    bf16* xb = (bf16*)d_ws;
    bf16* wp = (bf16*)((char*)d_ws + x_bytes);
    cvt_x_kernel<<<2048, 256, 0, stream>>>(x, xb, (long)BATCH * INSIZE / 4);
    cvt_w_kernel<<<dim3(NT, FEAT), 256, 0, stream>>>(w, wp);
    gemm_band_kernel<<<dim3(BATCH/BM, NT), 256, 0, stream>>>(xb, wp, bias, out);
  } else {
    naive_kernel<<<(long)BATCH * OUTCOLS / 256, 256, 0, stream>>>(x, w, bias, out);
  }
}